// Round 3
// baseline (94.184 us; speedup 1.0000x reference)
//
#include <hip/hip_runtime.h>

// Fixed problem shape
constexpr int BS = 16, F = 4086, C = 512, SPK = 2, L = 16, STEP = 8;
constexpr int T    = (F - 1) * STEP + L;   // 32696
constexpr int ROWS = BS * F;               // 65376
constexpr int OUT_N = BS * SPK * T;        // 1046272
constexpr int WAVES = 4;
constexpr int BLOCK = WAVES * 64;
constexpr int FR  = 4;                     // frames per wave
constexpr int FPB = WAVES * FR;            // 16 frames per block
constexpr int GRID_A = ROWS / FPB;         // 4086 exactly

// ---- cross-lane helpers (identical to passing r2 kernel) --------------------
template <int CTRL>
__device__ __forceinline__ float dppq(float x) {
    int i = __builtin_bit_cast(int, x);
    i = __builtin_amdgcn_update_dpp(i, i, CTRL, 0xf, 0xf, true);
    return __builtin_bit_cast(float, i);
}
template <int OFF>
__device__ __forceinline__ float swz(float x) {
    int i = __builtin_bit_cast(int, x);
    i = __builtin_amdgcn_ds_swizzle(i, OFF);
    return __builtin_bit_cast(float, i);
}

// Ascending-mask butterfly fold of v[32] across 64 lanes (verified r2).
// Lane L ends with value index o(L) = 5-bit bit-reversal of L&31.
__device__ __forceinline__ float fold32(float v[32], int lane) {
    const bool h1 = lane & 1, h2 = lane & 2, h4 = lane & 4, h8 = lane & 8, h16 = lane & 16;
#pragma unroll
    for (int i = 0; i < 16; ++i) {               // m=1 : DPP quad_perm
        const float s = h1 ? v[i] : v[i + 16];
        const float k = h1 ? v[i + 16] : v[i];
        v[i] = k + dppq<0xB1>(s);
    }
#pragma unroll
    for (int i = 0; i < 8; ++i) {                // m=2 : DPP quad_perm
        const float s = h2 ? v[i] : v[i + 8];
        const float k = h2 ? v[i + 8] : v[i];
        v[i] = k + dppq<0x4E>(s);
    }
#pragma unroll
    for (int i = 0; i < 4; ++i) {                // m=4 : ds_swizzle
        const float s = h4 ? v[i] : v[i + 4];
        const float k = h4 ? v[i + 4] : v[i];
        v[i] = k + swz<0x101F>(s);
    }
#pragma unroll
    for (int i = 0; i < 2; ++i) {                // m=8 : ds_swizzle
        const float s = h8 ? v[i] : v[i + 2];
        const float k = h8 ? v[i + 2] : v[i];
        v[i] = k + swz<0x201F>(s);
    }
    {                                            // m=16 : ds_swizzle
        const float s = h16 ? v[0] : v[1];
        const float k = h16 ? v[1] : v[0];
        v[0] = k + swz<0x401F>(s);
    }
    return v[0] + __shfl_xor(v[0], 32, 64);
}

__device__ __forceinline__ unsigned short f32_to_bf16_rne(float f) {
    unsigned int u = __builtin_bit_cast(unsigned int, f);
    u += 0x7fffu + ((u >> 16) & 1u);
    return (unsigned short)(u >> 16);
}

// ---- kernel A: masked projection -> proj[row][32] ---------------------------
__global__ __launch_bounds__(BLOCK, 4) void decoder_proj_kernel(
    const float* __restrict__ inp,   // [BS][F][C]
    const float* __restrict__ mask,  // [BS][F][C][SPK]
    const float* __restrict__ W,     // [C][L]
    float* __restrict__ dst)         // proj[ROWS][32]
{
    // wT[l][j] packs bf16(W[2j][l]) in lo, bf16(W[2j+1][l]) in hi  -> 16 KB
    __shared__ unsigned int wT[L * (C / 2)];

    const int tid = threadIdx.x;

    // Stage: thread t owns W rows 2t, 2t+1 (256 threads cover all 512 rows).
    {
        const float4* r0 = reinterpret_cast<const float4*>(W + (2 * tid) * L);
        const float4* r1 = reinterpret_cast<const float4*>(W + (2 * tid + 1) * L);
        float a[L], b[L];
#pragma unroll
        for (int q = 0; q < 4; ++q) {
            const float4 x = r0[q], y = r1[q];
            a[4*q+0]=x.x; a[4*q+1]=x.y; a[4*q+2]=x.z; a[4*q+3]=x.w;
            b[4*q+0]=y.x; b[4*q+1]=y.y; b[4*q+2]=y.z; b[4*q+3]=y.w;
        }
#pragma unroll
        for (int l = 0; l < L; ++l) {
            const unsigned int d = (unsigned int)f32_to_bf16_rne(a[l])
                                 | ((unsigned int)f32_to_bf16_rne(b[l]) << 16);
            wT[l * (C / 2) + tid] = d;   // bank = tid%32 -> conflict-free
        }
    }
    __syncthreads();

    const int wave = tid >> 6, lane = tid & 63;
    const int row0 = blockIdx.x * FPB + wave * FR;

    const int o = ((lane & 1) << 4) | (((lane >> 1) & 1) << 3) | (((lane >> 2) & 1) << 2)
                | (((lane >> 3) & 1) << 1) | ((lane >> 4) & 1);

    // lane owns channels c = 8*lane .. 8*lane+7
    float4 iA0, iA1, mA0, mA1, mA2, mA3;
    float4 iB0, iB1, mB0, mB1, mB2, mB3;

    auto load = [&](int row, float4& i0, float4& i1,
                    float4& m0, float4& m1, float4& m2, float4& m3) {
        const float4* ir = reinterpret_cast<const float4*>(inp + (size_t)row * C + 8 * lane);
        const float4* mr = reinterpret_cast<const float4*>(mask + (size_t)row * C * SPK + 16 * lane);
        i0 = ir[0]; i1 = ir[1];
        m0 = mr[0]; m1 = mr[1]; m2 = mr[2]; m3 = mr[3];
    };

    const int4* wT4 = reinterpret_cast<const int4*>(wT);

    auto compute = [&](const float4& i0, const float4& i1,
                       const float4& m0, const float4& m1,
                       const float4& m2, const float4& m3) -> float {
        // p0[k], p1[k]: x*mask for speaker 0/1 at c = 8*lane + k
        float p0[8], p1[8];
        p0[0]=i0.x*m0.x; p1[0]=i0.x*m0.y;  p0[1]=i0.y*m0.z; p1[1]=i0.y*m0.w;
        p0[2]=i0.z*m1.x; p1[2]=i0.z*m1.y;  p0[3]=i0.w*m1.z; p1[3]=i0.w*m1.w;
        p0[4]=i1.x*m2.x; p1[4]=i1.x*m2.y;  p0[5]=i1.y*m2.z; p1[5]=i1.y*m2.w;
        p0[6]=i1.z*m3.x; p1[6]=i1.z*m3.y;  p0[7]=i1.w*m3.z; p1[7]=i1.w*m3.w;

        float v[32];
#pragma unroll
        for (int j = 0; j < 32; ++j) v[j] = 0.f;

#pragma unroll
        for (int l = 0; l < L; ++l) {
            // 8 bf16 W values for c=8*lane..8*lane+7, row l: one conflict-free b128
            const int4 wd = wT4[l * (C / 8) + lane];
            const int d0 = wd.x, d1 = wd.y, d2 = wd.z, d3 = wd.w;
            float w[8];
            w[0] = __builtin_bit_cast(float, d0 << 16);
            w[1] = __builtin_bit_cast(float, d0 & 0xffff0000);
            w[2] = __builtin_bit_cast(float, d1 << 16);
            w[3] = __builtin_bit_cast(float, d1 & 0xffff0000);
            w[4] = __builtin_bit_cast(float, d2 << 16);
            w[5] = __builtin_bit_cast(float, d2 & 0xffff0000);
            w[6] = __builtin_bit_cast(float, d3 << 16);
            w[7] = __builtin_bit_cast(float, d3 & 0xffff0000);
#pragma unroll
            for (int k = 0; k < 8; ++k) {
                v[l]      = fmaf(p0[k], w[k], v[l]);
                v[16 + l] = fmaf(p1[k], w[k], v[16 + l]);
            }
        }
        return fold32(v, lane);
    };

    auto store = [&](int row, float val) {
        if (lane < 32) dst[(size_t)row * 32 + o] = val;   // 128B/wave contiguous
    };

    // double-buffered pipeline over FR=4 frames
    load(row0 + 0, iA0, iA1, mA0, mA1, mA2, mA3);
    load(row0 + 1, iB0, iB1, mB0, mB1, mB2, mB3);
    store(row0 + 0, compute(iA0, iA1, mA0, mA1, mA2, mA3));
    load(row0 + 2, iA0, iA1, mA0, mA1, mA2, mA3);
    store(row0 + 1, compute(iB0, iB1, mB0, mB1, mB2, mB3));
    load(row0 + 3, iB0, iB1, mB0, mB1, mB2, mB3);
    store(row0 + 2, compute(iA0, iA1, mA0, mA1, mA2, mA3));
    store(row0 + 3, compute(iB0, iB1, mB0, mB1, mB2, mB3));
}

// ---- kernel B: overlap-and-add gather ---------------------------------------
__global__ __launch_bounds__(256) void overlap_add_kernel(
    const float* __restrict__ proj,  // [ROWS][32]  (32 = s*16 + l)
    float* __restrict__ out)         // [BS][SPK][T]
{
    const int idx = blockIdx.x * blockDim.x + threadIdx.x;
    if (idx >= OUT_N) return;
    const int b = idx / (SPK * T);
    const int r = idx - b * (SPK * T);
    const int s = r / T;
    const int t = r - s * T;
    const int f0 = t >> 3, l0 = t & 7;
    float acc = 0.f;
    if (t < F * STEP) acc += proj[(size_t)(b * F + f0) * 32 + s * 16 + l0];
    if (t >= STEP)    acc += proj[(size_t)(b * F + f0 - 1) * 32 + s * 16 + 8 + l0];
    out[idx] = acc;
}

extern "C" void kernel_launch(void* const* d_in, const int* in_sizes, int n_in,
                              void* d_out, int out_size, void* d_ws, size_t ws_size,
                              hipStream_t stream) {
    const float* inp  = (const float*)d_in[0];
    const float* mask = (const float*)d_in[1];
    const float* W    = (const float*)d_in[2];
    float* out = (float*)d_out;

    float* proj = (float*)d_ws;  // 8.37 MB needed; ws is ample
    decoder_proj_kernel<<<GRID_A, BLOCK, 0, stream>>>(inp, mask, W, proj);
    overlap_add_kernel<<<(OUT_N + 255) / 256, 256, 0, stream>>>(proj, out);
}